// Round 14
// baseline (613.150 us; speedup 1.0000x reference)
//
#include <hip/hip_runtime.h>
#include <hip/hip_bf16.h>

// Problem constants (fixed by the reference)
#define B_ 4
#define T_ 2048
#define D_ 1024
#define H_ 16
#define DH 64
#define NF 32
#define BH (B_*H_)
#define M_ROWS (B_*T_)   // 8192

// Q pre-scale: 1/sqrt(Dh) = 0.125 exactly (power of two -> exact in bf16).
// Softmax uses __expf (fast intrinsic). NOT __builtin_exp2f (OCML fixup
// branches, round-7 regression), NOT inline-asm v_exp_f32 (round-3 hazard).
#define QSCALE 0.125f

using u16 = unsigned short;
using u32 = unsigned int;

typedef __bf16 bf16x8 __attribute__((ext_vector_type(8)));
typedef float  f32x4  __attribute__((ext_vector_type(4)));
typedef float  f32x16 __attribute__((ext_vector_type(16)));

__device__ __forceinline__ u16 f2bf(float f) {
  u32 u = __float_as_uint(f);
  u32 r = u + 0x7fffu + ((u >> 16) & 1u);   // RNE
  return (u16)(r >> 16);
}
__device__ __forceinline__ u16 f2bf_hw(float f) {
  __bf16 h = (__bf16)f;
  return *(u16*)&h;
}
__device__ __forceinline__ u32 pack2(float lo, float hi) {
  return (u32)f2bf_hw(lo) | ((u32)f2bf_hw(hi) << 16);
}
__device__ __forceinline__ float bf2f(u16 h) {
  return __uint_as_float(((u32)h) << 16);
}

// Cross-half exchange on the VALU pipe. Semantics verified (r10 fallback ==
// r11 asm, both passed): a <- {lo: a.lo, hi: b.lo}, b <- {lo: a.hi, hi: b.hi}.
__device__ __forceinline__ void pl32swap(u32 a, u32 b, u32& x, u32& y) {
  x = a; y = b;
  asm("s_nop 1\n\t"
      "v_permlane32_swap_b32 %0, %1"
      : "+v"(x), "+v"(y));
}

__device__ __forceinline__ void gload_lds16(const void* g, void* l) {
  __builtin_amdgcn_global_load_lds((__attribute__((address_space(1))) void*)(g),
                                   (__attribute__((address_space(3))) void*)(l),
                                   16, 0, 0);
}

// ---------------------------------------------------------------------------
// Merged prep: f32->bf16 of x / qkv_w / proj_w + sin/cos table, one launch.
__device__ __forceinline__ void cvt8(const float* __restrict__ in,
                                     u16* __restrict__ out, long idx) {
  const float4* p = (const float4*)in + idx * 2;
  float4 a = p[0], b = p[1];
  u32 o0 = (u32)f2bf(a.x) | ((u32)f2bf(a.y) << 16);
  u32 o1 = (u32)f2bf(a.z) | ((u32)f2bf(a.w) << 16);
  u32 o2 = (u32)f2bf(b.x) | ((u32)f2bf(b.y) << 16);
  u32 o3 = (u32)f2bf(b.z) | ((u32)f2bf(b.w) << 16);
  ((uint4*)out)[idx] = make_uint4(o0, o1, o2, o3);
}

__global__ __launch_bounds__(256)
void prep_kernel(const float* __restrict__ x, u16* __restrict__ xb,
                 const float* __restrict__ qkv_w, u16* __restrict__ wqkv,
                 const float* __restrict__ proj_w, u16* __restrict__ wproj,
                 const float* __restrict__ coords, const float* __restrict__ inv_freq,
                 const int* __restrict__ axes, float* __restrict__ sc) {
  long idx = (long)blockIdx.x * 256 + threadIdx.x;
  const long n1 = (long)M_ROWS * D_ / 8;            // 1048576
  const long n2 = n1 + 3L * D_ * D_ / 8;            // +393216
  const long n3 = n2 + (long)D_ * D_ / 8;           // +131072
  const long n4 = n3 + (long)B_ * T_ * NF;          // +262144 = 1835008 total
  if (idx < n1) {
    cvt8(x, xb, idx);
  } else if (idx < n2) {
    cvt8(qkv_w, wqkv, idx - n1);
  } else if (idx < n3) {
    cvt8(proj_w, wproj, idx - n2);
  } else if (idx < n4) {
    long j = idx - n3;
    int f = (int)(j & 31);
    long bt = j >> 5;
    float c = coords[bt * 3 + axes[f]];
    float ang = c * inv_freq[f];
    sc[bt * 64 + f]      = sinf(ang);
    sc[bt * 64 + 32 + f] = cosf(ang);
  }
}

// ---------------------------------------------------------------------------
// Fused QKV GEMM + bias + RoPE + head-split + V-TRANSPOSE.  (r13, verified)
__global__ __launch_bounds__(256, 2)
void gemm_qkv(const u16* __restrict__ A, const u16* __restrict__ Bt,
              const float* __restrict__ bias, const float* __restrict__ sc,
              u16* __restrict__ qr, u16* __restrict__ kr, u16* __restrict__ vt) {
  const int N = 3 * D_, K = D_;
  __shared__ u16 SMEM[128 * 64 * 2];     // As | Bs ; aliased as Vsm in epilogue
  u16* As = SMEM;
  u16* Bs = SMEM + 128 * 64;
  int nb = N >> 7;                       // 24
  int bid = blockIdx.x;
  int nwg = gridDim.x;                   // 1536, %8 == 0
  int cpx = nwg >> 3;
  bid = (bid & 7) * cpx + (bid >> 3);    // bijective XCD swizzle
  int bm = bid / nb, bn = bid % nb;
  long m0 = (long)bm << 7, n0 = (long)bn << 7;
  int tid = threadIdx.x;
  int lane = tid & 63, w = tid >> 6;
  int g = lane >> 4, lr = lane & 15;
  int wm = w >> 1, wn = w & 1;

  f32x4 acc[4][4] = {};

  for (int kt = 0; kt < K; kt += 64) {
    __syncthreads();
    #pragma unroll
    for (int j = 0; j < 4; ++j) {
      int ob = j * 4096 + tid * 16;
      int row = ob >> 7, col = (ob & 127) >> 1;
      u16* ldsA = As + j * 2048 + w * 512;
      u16* ldsB = Bs + j * 2048 + w * 512;
      gload_lds16(A + (m0 + row) * K + kt + col, ldsA);
      gload_lds16(Bt + (n0 + row) * K + kt + col, ldsB);
    }
    __syncthreads();
    #pragma unroll
    for (int kk = 0; kk < 2; ++kk) {
      bf16x8 af[4], bfr[4];
      #pragma unroll
      for (int i = 0; i < 4; ++i)
        af[i] = *(const bf16x8*)(As + (wm * 64 + i * 16 + lr) * 64 + kk * 32 + g * 8);
      #pragma unroll
      for (int i = 0; i < 4; ++i)
        bfr[i] = *(const bf16x8*)(Bs + (wn * 64 + i * 16 + lr) * 64 + kk * 32 + g * 8);
      #pragma unroll
      for (int mi = 0; mi < 4; ++mi)
        #pragma unroll
        for (int nj = 0; nj < 4; ++nj)
          acc[mi][nj] = __builtin_amdgcn_mfma_f32_16x16x32_bf16(af[mi], bfr[nj], acc[mi][nj], 0, 0, 0);
    }
  }

  // ---- fused epilogue ----
  int part = (int)(n0 >> 10);                    // 0=Q,1=K,2=V (block-uniform)
  int b = (int)(m0 >> 11), t0 = (int)(m0 & 2047);
  float bv[4];
  #pragma unroll
  for (int nj = 0; nj < 4; ++nj)
    bv[nj] = bias[n0 + wn * 64 + nj * 16 + lr];

  if (part == 2) {
    int h0 = (int)((n0 & 1023) >> 6);
    u16* Vsm = SMEM;                     // 128*72 u16 = 18 KB
    #pragma unroll
    for (int hsel = 0; hsel < 2; ++hsel) {
      __syncthreads();
      if (wn == hsel) {
        #pragma unroll
        for (int mi = 0; mi < 4; ++mi)
          #pragma unroll
          for (int i = 0; i < 4; ++i) {
            int lrow = wm * 64 + mi * 16 + g * 4 + i;
            #pragma unroll
            for (int nj = 0; nj < 4; ++nj)
              Vsm[lrow * 72 + nj * 16 + lr] = f2bf(acc[mi][nj][i] + bv[nj]);
          }
      }
      __syncthreads();
      int d = tid >> 2, tc = tid & 3;
      long obase = ((long)((b * 16 + h0 + hsel) * DH + d)) * T_ + t0 + tc * 32;
      #pragma unroll
      for (int c = 0; c < 4; ++c) {
        u32 o[4];
        #pragma unroll
        for (int j = 0; j < 4; ++j) {
          u16 lo = Vsm[(tc * 32 + c * 8 + 2 * j)     * 72 + d];
          u16 hi = Vsm[(tc * 32 + c * 8 + 2 * j + 1) * 72 + d];
          o[j] = (u32)lo | ((u32)hi << 16);
        }
        *(uint4*)(vt + obase + c * 8) = make_uint4(o[0], o[1], o[2], o[3]);
      }
    }
  } else {
    int h = ((int)(n0 & 1023) >> 6) + wn;        // head (wave-uniform)
    u16* outp = part ? kr : qr;
    float fac = part ? 1.0f : QSCALE;
    #pragma unroll
    for (int mi = 0; mi < 4; ++mi) {
      #pragma unroll
      for (int i = 0; i < 4; ++i) {
        long row = m0 + wm * 64 + mi * 16 + g * 4 + i;   // global bt
        long obase = ((long)((b * 16 + h)) * T_ + (row & 2047)) * 64;
        const float* scp = sc + row * 64;
        #pragma unroll
        for (int nj = 0; nj < 2; ++nj) {
          int d = nj * 16 + lr;
          float sn = scp[d], cs = scp[32 + d];
          float t1 = acc[mi][nj][i]     + bv[nj];
          float t2 = acc[mi][nj + 2][i] + bv[nj + 2];
          outp[obase + d]      = f2bf((t1 * cs - t2 * sn) * fac);
          outp[obase + 32 + d] = f2bf((t1 * sn + t2 * cs) * fac);
        }
      }
    }
  }
}

// ---------------------------------------------------------------------------
// plain bf16 GEMM (proj): C[M,N] = A[M,K] @ Bt[N,K]^T + bias, f32 out
__global__ __launch_bounds__(256, 2)
void gemm_bt(const u16* __restrict__ A, const u16* __restrict__ Bt,
             const float* __restrict__ bias, float* __restrict__ Cout,
             int M, int N, int K) {
  __shared__ u16 As[128 * 64];
  __shared__ u16 Bs[128 * 64];
  int nb = N >> 7;
  int bid = blockIdx.x;
  int nwg = gridDim.x;
  if ((nwg & 7) == 0) {
    int c = nwg >> 3;
    bid = (bid & 7) * c + (bid >> 3);
  }
  int bm = bid / nb, bn = bid % nb;
  long m0 = (long)bm << 7, n0 = (long)bn << 7;
  int tid = threadIdx.x;
  int lane = tid & 63, w = tid >> 6;
  int g = lane >> 4, lr = lane & 15;
  int wm = w >> 1, wn = w & 1;

  f32x4 acc[4][4] = {};

  for (int kt = 0; kt < K; kt += 64) {
    __syncthreads();
    #pragma unroll
    for (int j = 0; j < 4; ++j) {
      int ob = j * 4096 + tid * 16;
      int row = ob >> 7, col = (ob & 127) >> 1;
      u16* ldsA = As + j * 2048 + w * 512;
      u16* ldsB = Bs + j * 2048 + w * 512;
      gload_lds16(A + (m0 + row) * K + kt + col, ldsA);
      gload_lds16(Bt + (n0 + row) * K + kt + col, ldsB);
    }
    __syncthreads();
    #pragma unroll
    for (int kk = 0; kk < 2; ++kk) {
      bf16x8 af[4], bfr[4];
      #pragma unroll
      for (int i = 0; i < 4; ++i)
        af[i] = *(const bf16x8*)(As + (wm * 64 + i * 16 + lr) * 64 + kk * 32 + g * 8);
      #pragma unroll
      for (int i = 0; i < 4; ++i)
        bfr[i] = *(const bf16x8*)(Bs + (wn * 64 + i * 16 + lr) * 64 + kk * 32 + g * 8);
      #pragma unroll
      for (int mi = 0; mi < 4; ++mi)
        #pragma unroll
        for (int nj = 0; nj < 4; ++nj)
          acc[mi][nj] = __builtin_amdgcn_mfma_f32_16x16x32_bf16(af[mi], bfr[nj], acc[mi][nj], 0, 0, 0);
    }
  }
  #pragma unroll
  for (int mi = 0; mi < 4; ++mi) {
    #pragma unroll
    for (int nj = 0; nj < 4; ++nj) {
      long col = n0 + wn * 64 + nj * 16 + lr;
      float bvv = bias[col];
      #pragma unroll
      for (int i = 0; i < 4; ++i) {
        long row = m0 + wm * 64 + mi * 16 + g * 4 + i;
        Cout[row * (long)N + col] = acc[mi][nj][i] + bvv;
      }
    }
  }
}

// ---------------------------------------------------------------------------
// Flash attention, KV-SPLIT: 1024 wgs = 64 bh x 8 q-chunks x 2 kv-halves.
// Each block runs the r12-verified body (KVBLK=64, 32 KB LDS, 64 q/wave,
// swapped 32x32 MFMA, P in registers, permlane32 exchange) over its 1024-key
// half and writes UNNORMALIZED partial O (bf16) + partial l (f32) -- exact
// under max-free softmax (no max rebasing; sums just add in the combiner).
// 4 independent blocks/CU (LDS 128 KB, VGPR<=128 via launch_bounds(256,4))
// -> 4 independent barrier groups per SIMD to fill the r13-diagnosed
// dependency-chain stalls (pipe-busy ~5.2k cy of 15.45k cy period).
__global__ __launch_bounds__(256, 4)
void attn_kernel(const u16* __restrict__ Qr, const u16* __restrict__ Kr,
                 const u16* __restrict__ Vt, u16* __restrict__ P,
                 float* __restrict__ L) {
  __shared__ u16 Ks[2][64 * 64];
  __shared__ u16 Vs[2][64 * 64];       // V^T tile: [d][t']
  int wg = (blockIdx.x & 7) * 128 + (blockIdx.x >> 3);  // XCD-chunked (1024 wgs)
  int bh = wg >> 4;                    // 16 wgs per bh (8 qc x 2 kv)
  int sub = wg & 15;
  int q0 = (sub >> 1) << 8;            // 256 q-rows per block
  int kv = sub & 1;
  int kb0 = kv << 10;                  // key-range base: 0 or 1024
  int b = bh >> 4, h = bh & 15;
  int tid = threadIdx.x;
  int lane = tid & 63, w = tid >> 6;
  int l5 = lane & 31, hb = lane >> 5;

  const long tbase = (long)bh * T_;
  const long vbase = (long)bh * DH;
  const int qs = q0 + w * 64;          // wave's 64 q rows

  // Q as the QK^T B-frags (32x32x16: col = l5 = q, k = hb*8+j), pre-scaled.
  bf16x8 bq0[4], bq1[4];
  #pragma unroll
  for (int s = 0; s < 4; ++s) {
    bq0[s] = *(const bf16x8*)(Qr + (tbase + qs + l5)      * DH + s * 16 + hb * 8);
    bq1[s] = *(const bf16x8*)(Qr + (tbase + qs + 32 + l5) * DH + s * 16 + hb * 8);
  }

  f32x16 oa00 = {}, oa01 = {};         // qb0: O^T d-halves
  f32x16 oa10 = {}, oa11 = {};         // qb1
  float ls0 = 0.f, ls1 = 0.f;

  const int sl = l5 & 7;               // swizzle key (row&7 == l5&7 for our reads)

  // stage one 64-key tile: linear LDS dest, inverse-swizzled global source
  auto STAGE = [&](int buf, int kb) {
    #pragma unroll
    for (int j = 0; j < 2; ++j) {
      int ob = j * 4096 + tid * 16;            // byte pos in 8KB tile
      int row = ob >> 7;
      int c = ((ob >> 4) & 7) ^ (row & 7);
      u16* ldsK = Ks[buf] + j * 2048 + w * 512;  // wave-uniform; HW adds lane*16
      u16* ldsV = Vs[buf] + j * 2048 + w * 512;
      gload_lds16(Kr + (tbase + kb + row) * DH + c * 8, ldsK);
      gload_lds16(Vt + (vbase + row) * T_ + kb + c * 8, ldsV);
    }
  };

  STAGE(0, kb0);
  asm volatile("s_waitcnt vmcnt(0)" ::: "memory");
  __builtin_amdgcn_s_barrier();
  __builtin_amdgcn_sched_barrier(0);

  int cur = 0;
  for (int kt = 0; kt < 16; ++kt) {
    if (kt + 1 < 16) STAGE(cur ^ 1, kb0 + (kt + 1) * 64);

    const u16* kbuf = Ks[cur];
    const u16* vbuf = Vs[cur];

    // S' = K Q^T for BOTH q-sub-tiles off ONE ak load per s-step
    f32x16 p00 = {}, p01 = {}, p10 = {}, p11 = {};
    #pragma unroll
    for (int s = 0; s < 4; ++s) {
      int c = ((2 * s + hb) ^ sl) * 8;
      bf16x8 ak0 = *(const bf16x8*)(kbuf + l5 * 64 + c);
      bf16x8 ak1 = *(const bf16x8*)(kbuf + (32 + l5) * 64 + c);
      p00 = __builtin_amdgcn_mfma_f32_32x32x16_bf16(ak0, bq0[s], p00, 0, 0, 0);
      p01 = __builtin_amdgcn_mfma_f32_32x32x16_bf16(ak1, bq0[s], p01, 0, 0, 0);
      p10 = __builtin_amdgcn_mfma_f32_32x32x16_bf16(ak0, bq1[s], p10, 0, 0, 0);
      p11 = __builtin_amdgcn_mfma_f32_32x32x16_bf16(ak1, bq1[s], p11, 0, 0, 0);
    }

    // max-free softmax + pack (both sub-tiles)
    u32 pA0[8], pB0[8], pA1[8], pB1[8];
    #pragma unroll
    for (int r4 = 0; r4 < 4; ++r4) {
      float a0 = __expf(p00[4 * r4 + 0]), a1 = __expf(p00[4 * r4 + 1]);
      float a2 = __expf(p00[4 * r4 + 2]), a3 = __expf(p00[4 * r4 + 3]);
      ls0 += (a0 + a1) + (a2 + a3);
      pA0[r4] = pack2(a0, a1); pB0[r4] = pack2(a2, a3);
      float b0 = __expf(p01[4 * r4 + 0]), b1 = __expf(p01[4 * r4 + 1]);
      float b2 = __expf(p01[4 * r4 + 2]), b3 = __expf(p01[4 * r4 + 3]);
      ls0 += (b0 + b1) + (b2 + b3);
      pA0[4 + r4] = pack2(b0, b1); pB0[4 + r4] = pack2(b2, b3);
      float c0 = __expf(p10[4 * r4 + 0]), c1 = __expf(p10[4 * r4 + 1]);
      float c2 = __expf(p10[4 * r4 + 2]), c3 = __expf(p10[4 * r4 + 3]);
      ls1 += (c0 + c1) + (c2 + c3);
      pA1[r4] = pack2(c0, c1); pB1[r4] = pack2(c2, c3);
      float d0 = __expf(p11[4 * r4 + 0]), d1 = __expf(p11[4 * r4 + 1]);
      float d2 = __expf(p11[4 * r4 + 2]), d3 = __expf(p11[4 * r4 + 3]);
      ls1 += (d0 + d1) + (d2 + d3);
      pA1[4 + r4] = pack2(d0, d1); pB1[4 + r4] = pack2(d2, d3);
    }

    // O^T += V^T P^T for BOTH sub-tiles off ONE av load per s2-step
    #pragma unroll
    for (int s2 = 0; s2 < 4; ++s2) {
      int c = ((2 * s2 + hb) ^ sl) * 8;
      bf16x8 av0 = *(const bf16x8*)(vbuf + l5 * 64 + c);
      bf16x8 av1 = *(const bf16x8*)(vbuf + (32 + l5) * 64 + c);
      u32 w0, w1, w2, w3;
      pl32swap(pA0[2 * s2], pA0[2 * s2 + 1], w0, w2);
      pl32swap(pB0[2 * s2], pB0[2 * s2 + 1], w1, w3);
      union { u32 u[4]; bf16x8 v; } bw0;
      bw0.u[0] = w0; bw0.u[1] = w1; bw0.u[2] = w2; bw0.u[3] = w3;
      oa00 = __builtin_amdgcn_mfma_f32_32x32x16_bf16(av0, bw0.v, oa00, 0, 0, 0);
      oa01 = __builtin_amdgcn_mfma_f32_32x32x16_bf16(av1, bw0.v, oa01, 0, 0, 0);
      pl32swap(pA1[2 * s2], pA1[2 * s2 + 1], w0, w2);
      pl32swap(pB1[2 * s2], pB1[2 * s2 + 1], w1, w3);
      union { u32 u[4]; bf16x8 v; } bw1;
      bw1.u[0] = w0; bw1.u[1] = w1; bw1.u[2] = w2; bw1.u[3] = w3;
      oa10 = __builtin_amdgcn_mfma_f32_32x32x16_bf16(av0, bw1.v, oa10, 0, 0, 0);
      oa11 = __builtin_amdgcn_mfma_f32_32x32x16_bf16(av1, bw1.v, oa11, 0, 0, 0);
    }

    // one barrier per tile; prefetch had the whole compute phase to land
    __builtin_amdgcn_sched_barrier(0);
    asm volatile("s_waitcnt vmcnt(0)" ::: "memory");
    __builtin_amdgcn_s_barrier();
    __builtin_amdgcn_sched_barrier(0);
    cur ^= 1;
  }

  // epilogue: UNNORMALIZED partial writes; combine kernel divides by total l.
  ls0 += __shfl_xor(ls0, 32);
  ls1 += __shfl_xor(ls1, 32);
  const long PS = (long)BH * T_ * DH;
  u16* Pout = P + (long)kv * PS;
  long row0 = (long)b * T_ + qs + l5;
  u16* ob0 = Pout + row0 * D_ + h * DH;
  u16* ob1 = ob0 + 32 * D_;            // row qs + 32 + l5
  #pragma unroll
  for (int r4 = 0; r4 < 4; ++r4) {
    u32 w0 = pack2(oa00[4 * r4 + 0], oa00[4 * r4 + 1]);
    u32 w1 = pack2(oa00[4 * r4 + 2], oa00[4 * r4 + 3]);
    *(uint2*)(ob0 + r4 * 8 + hb * 4) = make_uint2(w0, w1);
    u32 w2 = pack2(oa01[4 * r4 + 0], oa01[4 * r4 + 1]);
    u32 w3 = pack2(oa01[4 * r4 + 2], oa01[4 * r4 + 3]);
    *(uint2*)(ob0 + 32 + r4 * 8 + hb * 4) = make_uint2(w2, w3);
    u32 w4 = pack2(oa10[4 * r4 + 0], oa10[4 * r4 + 1]);
    u32 w5 = pack2(oa10[4 * r4 + 2], oa10[4 * r4 + 3]);
    *(uint2*)(ob1 + r4 * 8 + hb * 4) = make_uint2(w4, w5);
    u32 w6 = pack2(oa11[4 * r4 + 0], oa11[4 * r4 + 1]);
    u32 w7 = pack2(oa11[4 * r4 + 2], oa11[4 * r4 + 3]);
    *(uint2*)(ob1 + 32 + r4 * 8 + hb * 4) = make_uint2(w6, w7);
  }
  if (hb == 0) {
    float* lp = L + (long)kv * (BH * (long)T_) + ((long)bh << 11);
    lp[qs + l5]      = ls0;
    lp[qs + 32 + l5] = ls1;
  }
}

// ---------------------------------------------------------------------------
// Combine: out = (P0 + P1) / (l0 + l1), elementwise; 8 elems/thread.
__global__ __launch_bounds__(256)
void combine_kernel(const u16* __restrict__ P, const float* __restrict__ L,
                    u16* __restrict__ out) {
  long idx = (long)blockIdx.x * 256 + threadIdx.x;
  if (idx >= (long)M_ROWS * D_ / 8) return;
  long e0 = idx << 3;                  // element offset in [B][T][D]
  long row = e0 >> 10;                 // b*T + t
  int col = (int)(e0 & 1023);
  int h = col >> 6;
  int b = (int)(row >> 11), t = (int)(row & 2047);
  long pl = ((long)(b * 16 + h) << 11) + t;      // bh*T + t
  const long PS = (long)BH * T_ * DH;
  const long LS = (long)BH * T_;
  float inv = 1.0f / (L[pl] + L[LS + pl]);
  uint4 u0 = *(const uint4*)(P + e0);
  uint4 u1 = *(const uint4*)(P + PS + e0);
  u32 a[4] = {u0.x, u0.y, u0.z, u0.w};
  u32 c[4] = {u1.x, u1.y, u1.z, u1.w};
  u32 o[4];
  #pragma unroll
  for (int j = 0; j < 4; ++j) {
    float lo = bf2f((u16)(a[j] & 0xffff)) + bf2f((u16)(c[j] & 0xffff));
    float hi = bf2f((u16)(a[j] >> 16))    + bf2f((u16)(c[j] >> 16));
    o[j] = pack2(lo * inv, hi * inv);
  }
  *(uint4*)(out + e0) = make_uint4(o[0], o[1], o[2], o[3]);
}

// ---------------------------------------------------------------------------
extern "C" void kernel_launch(void* const* d_in, const int* in_sizes, int n_in,
                              void* d_out, int out_size, void* d_ws, size_t ws_size,
                              hipStream_t stream) {
  const float* x        = (const float*)d_in[0];
  const float* coords   = (const float*)d_in[1];
  const float* qkv_w    = (const float*)d_in[2];
  const float* qkv_b    = (const float*)d_in[3];
  const float* proj_w   = (const float*)d_in[4];
  const float* proj_b   = (const float*)d_in[5];
  const float* inv_freq = (const float*)d_in[6];
  const int*   axes     = (const int*)d_in[7];
  float* out = (float*)d_out;

  char* ws = (char*)d_ws;
  size_t off = 0;
  auto alloc = [&](size_t bytes) -> char* {
    char* p = ws + off;
    off += (bytes + 255) & ~(size_t)255;
    return p;
  };
  u16*   xb     = (u16*)  alloc((size_t)M_ROWS * D_ * 2);
  u16*   wqkv   = (u16*)  alloc((size_t)3 * D_ * D_ * 2);
  u16*   wproj  = (u16*)  alloc((size_t)D_ * D_ * 2);
  float* sc     = (float*)alloc((size_t)M_ROWS * 64 * 4);
  u16*   qr     = (u16*)  alloc((size_t)BH * T_ * DH * 2);
  u16*   kr     = (u16*)  alloc((size_t)BH * T_ * DH * 2);
  u16*   vt     = (u16*)  alloc((size_t)BH * T_ * DH * 2);
  u16*   Pp     = (u16*)  alloc((size_t)2 * BH * T_ * DH * 2);   // partial O x2
  float* Lp     = (float*)alloc((size_t)2 * BH * T_ * 4);        // partial l x2
  u16*   aout   = xb;      // xb dead after gemm_qkv; reuse for combined attn out

  prep_kernel<<<7168, 256, 0, stream>>>(x, xb, qkv_w, wqkv, proj_w, wproj,
                                        coords, inv_freq, axes, sc);
  gemm_qkv<<<(M_ROWS / 128) * (3 * D_ / 128), 256, 0, stream>>>(xb, wqkv, qkv_b, sc,
                                                                qr, kr, vt);
  attn_kernel<<<1024, 256, 0, stream>>>(qr, kr, vt, Pp, Lp);
  combine_kernel<<<(M_ROWS * D_ / 8 + 255) / 256, 256, 0, stream>>>(Pp, Lp, aout);
  gemm_bt<<<(M_ROWS / 128) * (D_ / 128), 256, 0, stream>>>(aout, wproj, proj_b, out,
                                                           M_ROWS, D_, D_);
}

// Round 15
// 197.131 us; speedup vs baseline: 3.1104x; 3.1104x over previous
//
#include <hip/hip_runtime.h>
#include <hip/hip_bf16.h>

// Problem constants (fixed by the reference)
#define B_ 4
#define T_ 2048
#define D_ 1024
#define H_ 16
#define DH 64
#define NF 32
#define BH (B_*H_)
#define M_ROWS (B_*T_)   // 8192

// Q pre-scale: 1/sqrt(Dh) = 0.125 exactly (power of two -> exact in bf16).
// Softmax uses __expf (fast intrinsic). NOT __builtin_exp2f (OCML fixup
// branches, round-7 regression), NOT inline-asm v_exp_f32 (round-3 hazard).
#define QSCALE 0.125f

using u16 = unsigned short;
using u32 = unsigned int;

typedef __bf16 bf16x8 __attribute__((ext_vector_type(8)));
typedef float  f32x4  __attribute__((ext_vector_type(4)));
typedef float  f32x16 __attribute__((ext_vector_type(16)));

__device__ __forceinline__ u16 f2bf(float f) {
  u32 u = __float_as_uint(f);
  u32 r = u + 0x7fffu + ((u >> 16) & 1u);   // RNE
  return (u16)(r >> 16);
}
__device__ __forceinline__ u16 f2bf_hw(float f) {
  __bf16 h = (__bf16)f;
  return *(u16*)&h;
}
__device__ __forceinline__ u32 pack2(float lo, float hi) {
  return (u32)f2bf_hw(lo) | ((u32)f2bf_hw(hi) << 16);
}
__device__ __forceinline__ float bf2f(u16 h) {
  return __uint_as_float(((u32)h) << 16);
}

// Cross-half exchange on the VALU pipe. Semantics verified (r10 fallback ==
// r11 asm, both passed): a <- {lo: a.lo, hi: b.lo}, b <- {lo: a.hi, hi: b.hi}.
__device__ __forceinline__ void pl32swap(u32 a, u32 b, u32& x, u32& y) {
  x = a; y = b;
  asm("s_nop 1\n\t"
      "v_permlane32_swap_b32 %0, %1"
      : "+v"(x), "+v"(y));
}

__device__ __forceinline__ void gload_lds16(const void* g, void* l) {
  __builtin_amdgcn_global_load_lds((__attribute__((address_space(1))) void*)(g),
                                   (__attribute__((address_space(3))) void*)(l),
                                   16, 0, 0);
}

// ---------------------------------------------------------------------------
// Merged prep: f32->bf16 of x / qkv_w / proj_w + sin/cos table, one launch.
// (validated in r14's passing run; memory-bound, branch is block-uniform
// except at the three segment seams)
__device__ __forceinline__ void cvt8(const float* __restrict__ in,
                                     u16* __restrict__ out, long idx) {
  const float4* p = (const float4*)in + idx * 2;
  float4 a = p[0], b = p[1];
  u32 o0 = (u32)f2bf(a.x) | ((u32)f2bf(a.y) << 16);
  u32 o1 = (u32)f2bf(a.z) | ((u32)f2bf(a.w) << 16);
  u32 o2 = (u32)f2bf(b.x) | ((u32)f2bf(b.y) << 16);
  u32 o3 = (u32)f2bf(b.z) | ((u32)f2bf(b.w) << 16);
  ((uint4*)out)[idx] = make_uint4(o0, o1, o2, o3);
}

__global__ __launch_bounds__(256)
void prep_kernel(const float* __restrict__ x, u16* __restrict__ xb,
                 const float* __restrict__ qkv_w, u16* __restrict__ wqkv,
                 const float* __restrict__ proj_w, u16* __restrict__ wproj,
                 const float* __restrict__ coords, const float* __restrict__ inv_freq,
                 const int* __restrict__ axes, float* __restrict__ sc) {
  long idx = (long)blockIdx.x * 256 + threadIdx.x;
  const long n1 = (long)M_ROWS * D_ / 8;            // 1048576
  const long n2 = n1 + 3L * D_ * D_ / 8;            // +393216
  const long n3 = n2 + (long)D_ * D_ / 8;           // +131072
  const long n4 = n3 + (long)B_ * T_ * NF;          // +262144 = 1835008 total
  if (idx < n1) {
    cvt8(x, xb, idx);
  } else if (idx < n2) {
    cvt8(qkv_w, wqkv, idx - n1);
  } else if (idx < n3) {
    cvt8(proj_w, wproj, idx - n2);
  } else if (idx < n4) {
    long j = idx - n3;
    int f = (int)(j & 31);
    long bt = j >> 5;
    float c = coords[bt * 3 + axes[f]];
    float ang = c * inv_freq[f];
    sc[bt * 64 + f]      = sinf(ang);
    sc[bt * 64 + 32 + f] = cosf(ang);
  }
}

// ---------------------------------------------------------------------------
// Fused QKV GEMM + bias + RoPE + head-split + V-TRANSPOSE.  (r13, verified)
__global__ __launch_bounds__(256, 2)
void gemm_qkv(const u16* __restrict__ A, const u16* __restrict__ Bt,
              const float* __restrict__ bias, const float* __restrict__ sc,
              u16* __restrict__ qr, u16* __restrict__ kr, u16* __restrict__ vt) {
  const int N = 3 * D_, K = D_;
  __shared__ u16 SMEM[128 * 64 * 2];     // As | Bs ; aliased as Vsm in epilogue
  u16* As = SMEM;
  u16* Bs = SMEM + 128 * 64;
  int nb = N >> 7;                       // 24
  int bid = blockIdx.x;
  int nwg = gridDim.x;                   // 1536, %8 == 0
  int cpx = nwg >> 3;
  bid = (bid & 7) * cpx + (bid >> 3);    // bijective XCD swizzle
  int bm = bid / nb, bn = bid % nb;
  long m0 = (long)bm << 7, n0 = (long)bn << 7;
  int tid = threadIdx.x;
  int lane = tid & 63, w = tid >> 6;
  int g = lane >> 4, lr = lane & 15;
  int wm = w >> 1, wn = w & 1;

  f32x4 acc[4][4] = {};

  for (int kt = 0; kt < K; kt += 64) {
    __syncthreads();
    #pragma unroll
    for (int j = 0; j < 4; ++j) {
      int ob = j * 4096 + tid * 16;
      int row = ob >> 7, col = (ob & 127) >> 1;
      u16* ldsA = As + j * 2048 + w * 512;
      u16* ldsB = Bs + j * 2048 + w * 512;
      gload_lds16(A + (m0 + row) * K + kt + col, ldsA);
      gload_lds16(Bt + (n0 + row) * K + kt + col, ldsB);
    }
    __syncthreads();
    #pragma unroll
    for (int kk = 0; kk < 2; ++kk) {
      bf16x8 af[4], bfr[4];
      #pragma unroll
      for (int i = 0; i < 4; ++i)
        af[i] = *(const bf16x8*)(As + (wm * 64 + i * 16 + lr) * 64 + kk * 32 + g * 8);
      #pragma unroll
      for (int i = 0; i < 4; ++i)
        bfr[i] = *(const bf16x8*)(Bs + (wn * 64 + i * 16 + lr) * 64 + kk * 32 + g * 8);
      #pragma unroll
      for (int mi = 0; mi < 4; ++mi)
        #pragma unroll
        for (int nj = 0; nj < 4; ++nj)
          acc[mi][nj] = __builtin_amdgcn_mfma_f32_16x16x32_bf16(af[mi], bfr[nj], acc[mi][nj], 0, 0, 0);
    }
  }

  // ---- fused epilogue ----
  int part = (int)(n0 >> 10);                    // 0=Q,1=K,2=V (block-uniform)
  int b = (int)(m0 >> 11), t0 = (int)(m0 & 2047);
  float bv[4];
  #pragma unroll
  for (int nj = 0; nj < 4; ++nj)
    bv[nj] = bias[n0 + wn * 64 + nj * 16 + lr];

  if (part == 2) {
    int h0 = (int)((n0 & 1023) >> 6);
    u16* Vsm = SMEM;                     // 128*72 u16 = 18 KB
    #pragma unroll
    for (int hsel = 0; hsel < 2; ++hsel) {
      __syncthreads();
      if (wn == hsel) {
        #pragma unroll
        for (int mi = 0; mi < 4; ++mi)
          #pragma unroll
          for (int i = 0; i < 4; ++i) {
            int lrow = wm * 64 + mi * 16 + g * 4 + i;
            #pragma unroll
            for (int nj = 0; nj < 4; ++nj)
              Vsm[lrow * 72 + nj * 16 + lr] = f2bf(acc[mi][nj][i] + bv[nj]);
          }
      }
      __syncthreads();
      int d = tid >> 2, tc = tid & 3;
      long obase = ((long)((b * 16 + h0 + hsel) * DH + d)) * T_ + t0 + tc * 32;
      #pragma unroll
      for (int c = 0; c < 4; ++c) {
        u32 o[4];
        #pragma unroll
        for (int j = 0; j < 4; ++j) {
          u16 lo = Vsm[(tc * 32 + c * 8 + 2 * j)     * 72 + d];
          u16 hi = Vsm[(tc * 32 + c * 8 + 2 * j + 1) * 72 + d];
          o[j] = (u32)lo | ((u32)hi << 16);
        }
        *(uint4*)(vt + obase + c * 8) = make_uint4(o[0], o[1], o[2], o[3]);
      }
    }
  } else {
    int h = ((int)(n0 & 1023) >> 6) + wn;        // head (wave-uniform)
    u16* outp = part ? kr : qr;
    float fac = part ? 1.0f : QSCALE;
    #pragma unroll
    for (int mi = 0; mi < 4; ++mi) {
      #pragma unroll
      for (int i = 0; i < 4; ++i) {
        long row = m0 + wm * 64 + mi * 16 + g * 4 + i;   // global bt
        long obase = ((long)((b * 16 + h)) * T_ + (row & 2047)) * 64;
        const float* scp = sc + row * 64;
        #pragma unroll
        for (int nj = 0; nj < 2; ++nj) {
          int d = nj * 16 + lr;
          float sn = scp[d], cs = scp[32 + d];
          float t1 = acc[mi][nj][i]     + bv[nj];
          float t2 = acc[mi][nj + 2][i] + bv[nj + 2];
          outp[obase + d]      = f2bf((t1 * cs - t2 * sn) * fac);
          outp[obase + 32 + d] = f2bf((t1 * sn + t2 * cs) * fac);
        }
      }
    }
  }
}

// ---------------------------------------------------------------------------
// plain bf16 GEMM (proj): C[M,N] = A[M,K] @ Bt[N,K]^T + bias, f32 out
__global__ __launch_bounds__(256, 2)
void gemm_bt(const u16* __restrict__ A, const u16* __restrict__ Bt,
             const float* __restrict__ bias, float* __restrict__ Cout,
             int M, int N, int K) {
  __shared__ u16 As[128 * 64];
  __shared__ u16 Bs[128 * 64];
  int nb = N >> 7;
  int bid = blockIdx.x;
  int nwg = gridDim.x;
  if ((nwg & 7) == 0) {
    int c = nwg >> 3;
    bid = (bid & 7) * c + (bid >> 3);
  }
  int bm = bid / nb, bn = bid % nb;
  long m0 = (long)bm << 7, n0 = (long)bn << 7;
  int tid = threadIdx.x;
  int lane = tid & 63, w = tid >> 6;
  int g = lane >> 4, lr = lane & 15;
  int wm = w >> 1, wn = w & 1;

  f32x4 acc[4][4] = {};

  for (int kt = 0; kt < K; kt += 64) {
    __syncthreads();
    #pragma unroll
    for (int j = 0; j < 4; ++j) {
      int ob = j * 4096 + tid * 16;
      int row = ob >> 7, col = (ob & 127) >> 1;
      u16* ldsA = As + j * 2048 + w * 512;
      u16* ldsB = Bs + j * 2048 + w * 512;
      gload_lds16(A + (m0 + row) * K + kt + col, ldsA);
      gload_lds16(Bt + (n0 + row) * K + kt + col, ldsB);
    }
    __syncthreads();
    #pragma unroll
    for (int kk = 0; kk < 2; ++kk) {
      bf16x8 af[4], bfr[4];
      #pragma unroll
      for (int i = 0; i < 4; ++i)
        af[i] = *(const bf16x8*)(As + (wm * 64 + i * 16 + lr) * 64 + kk * 32 + g * 8);
      #pragma unroll
      for (int i = 0; i < 4; ++i)
        bfr[i] = *(const bf16x8*)(Bs + (wn * 64 + i * 16 + lr) * 64 + kk * 32 + g * 8);
      #pragma unroll
      for (int mi = 0; mi < 4; ++mi)
        #pragma unroll
        for (int nj = 0; nj < 4; ++nj)
          acc[mi][nj] = __builtin_amdgcn_mfma_f32_16x16x32_bf16(af[mi], bfr[nj], acc[mi][nj], 0, 0, 0);
    }
  }
  #pragma unroll
  for (int mi = 0; mi < 4; ++mi) {
    #pragma unroll
    for (int nj = 0; nj < 4; ++nj) {
      long col = n0 + wn * 64 + nj * 16 + lr;
      float bvv = bias[col];
      #pragma unroll
      for (int i = 0; i < 4; ++i) {
        long row = m0 + wm * 64 + mi * 16 + g * 4 + i;
        Cout[row * (long)N + col] = acc[mi][nj][i] + bvv;
      }
    }
  }
}

// ---------------------------------------------------------------------------
// Flash attention (r13-verified, 103 us): swapped-operand 32x32x16, P in
// registers, 64 q-rows/wave, KVBLK=128 (two r12-layout 64-key sub-tiles per
// staged tile), permlane32 exchange, max-free softmax via __expf, K/V
// XOR-swizzled, 2-phase prefetch, XCD-chunked 512-wg grid (8 bh per XCD ->
// K/V L2-fit). r14's KV-split variant (4 blocks/CU) thrashed L2 (8 MB
// resident K/V footprint vs 4 MB per-XCD L2 -> 2.1 GB traffic, 4.7x slower);
// this config sits exactly at the L2 boundary and is the measured optimum.
__global__ __launch_bounds__(256, 2)
void attn_kernel(const u16* __restrict__ Qr, const u16* __restrict__ Kr,
                 const u16* __restrict__ Vt, u16* __restrict__ Aout) {
  __shared__ u16 Ks[2][2][64 * 64];
  __shared__ u16 Vs[2][2][64 * 64];    // V^T sub-tiles: [d][t']
  int wg = (blockIdx.x & 7) * 64 + (blockIdx.x >> 3);   // XCD-chunked (512 wgs)
  int bh = wg >> 3;
  int b = bh >> 4, h = bh & 15;
  int q0 = (wg & 7) << 8;              // 256 q-rows per block
  int tid = threadIdx.x;
  int lane = tid & 63, w = tid >> 6;
  int l5 = lane & 31, hb = lane >> 5;

  const long tbase = (long)bh * T_;
  const long vbase = (long)bh * DH;
  const int qs = q0 + w * 64;          // wave's 64 q rows

  // Q as the QK^T B-frags (32x32x16: col = l5 = q, k = hb*8+j), pre-scaled.
  bf16x8 bq0[4], bq1[4];
  #pragma unroll
  for (int s = 0; s < 4; ++s) {
    bq0[s] = *(const bf16x8*)(Qr + (tbase + qs + l5)      * DH + s * 16 + hb * 8);
    bq1[s] = *(const bf16x8*)(Qr + (tbase + qs + 32 + l5) * DH + s * 16 + hb * 8);
  }

  f32x16 oa00 = {}, oa01 = {};         // qb0: O^T d-halves
  f32x16 oa10 = {}, oa11 = {};         // qb1
  float ls0 = 0.f, ls1 = 0.f;

  const int sl = l5 & 7;               // swizzle key (row&7 == l5&7 for our reads)

  // stage one 128-key tile (two 64-key sub-tiles, r12-identical layout each):
  // linear LDS dest, inverse-swizzled global source
  auto STAGE = [&](int buf, int kb) {
    #pragma unroll
    for (int sub = 0; sub < 2; ++sub) {
      #pragma unroll
      for (int j = 0; j < 2; ++j) {
        int ob = j * 4096 + tid * 16;          // byte pos in 8KB sub-tile
        int row = ob >> 7;
        int c = ((ob >> 4) & 7) ^ (row & 7);
        u16* ldsK = Ks[buf][sub] + j * 2048 + w * 512;
        u16* ldsV = Vs[buf][sub] + j * 2048 + w * 512;
        gload_lds16(Kr + (tbase + kb + sub * 64 + row) * DH + c * 8, ldsK);
        gload_lds16(Vt + (vbase + row) * T_ + kb + sub * 64 + c * 8, ldsV);
      }
    }
  };

  STAGE(0, 0);
  asm volatile("s_waitcnt vmcnt(0)" ::: "memory");
  __builtin_amdgcn_s_barrier();
  __builtin_amdgcn_sched_barrier(0);

  int cur = 0;
  for (int kt = 0; kt < T_ / 128; ++kt) {
    if (kt + 1 < T_ / 128) STAGE(cur ^ 1, (kt + 1) * 128);

    #pragma unroll
    for (int h2 = 0; h2 < 2; ++h2) {
      const u16* kbuf = Ks[cur][h2];
      const u16* vbuf = Vs[cur][h2];

      // S' = K Q^T for BOTH q-sub-tiles off ONE ak load per s-step
      f32x16 p00 = {}, p01 = {}, p10 = {}, p11 = {};
      #pragma unroll
      for (int s = 0; s < 4; ++s) {
        int c = ((2 * s + hb) ^ sl) * 8;
        bf16x8 ak0 = *(const bf16x8*)(kbuf + l5 * 64 + c);
        bf16x8 ak1 = *(const bf16x8*)(kbuf + (32 + l5) * 64 + c);
        p00 = __builtin_amdgcn_mfma_f32_32x32x16_bf16(ak0, bq0[s], p00, 0, 0, 0);
        p01 = __builtin_amdgcn_mfma_f32_32x32x16_bf16(ak1, bq0[s], p01, 0, 0, 0);
        p10 = __builtin_amdgcn_mfma_f32_32x32x16_bf16(ak0, bq1[s], p10, 0, 0, 0);
        p11 = __builtin_amdgcn_mfma_f32_32x32x16_bf16(ak1, bq1[s], p11, 0, 0, 0);
      }

      // max-free softmax + pack (both sub-tiles)
      u32 pA0[8], pB0[8], pA1[8], pB1[8];
      #pragma unroll
      for (int r4 = 0; r4 < 4; ++r4) {
        float a0 = __expf(p00[4 * r4 + 0]), a1 = __expf(p00[4 * r4 + 1]);
        float a2 = __expf(p00[4 * r4 + 2]), a3 = __expf(p00[4 * r4 + 3]);
        ls0 += (a0 + a1) + (a2 + a3);
        pA0[r4] = pack2(a0, a1); pB0[r4] = pack2(a2, a3);
        float b0 = __expf(p01[4 * r4 + 0]), b1 = __expf(p01[4 * r4 + 1]);
        float b2 = __expf(p01[4 * r4 + 2]), b3 = __expf(p01[4 * r4 + 3]);
        ls0 += (b0 + b1) + (b2 + b3);
        pA0[4 + r4] = pack2(b0, b1); pB0[4 + r4] = pack2(b2, b3);
        float c0 = __expf(p10[4 * r4 + 0]), c1 = __expf(p10[4 * r4 + 1]);
        float c2 = __expf(p10[4 * r4 + 2]), c3 = __expf(p10[4 * r4 + 3]);
        ls1 += (c0 + c1) + (c2 + c3);
        pA1[r4] = pack2(c0, c1); pB1[r4] = pack2(c2, c3);
        float d0 = __expf(p11[4 * r4 + 0]), d1 = __expf(p11[4 * r4 + 1]);
        float d2 = __expf(p11[4 * r4 + 2]), d3 = __expf(p11[4 * r4 + 3]);
        ls1 += (d0 + d1) + (d2 + d3);
        pA1[4 + r4] = pack2(d0, d1); pB1[4 + r4] = pack2(d2, d3);
      }

      // O^T += V^T P^T for BOTH sub-tiles off ONE av load per s2-step
      #pragma unroll
      for (int s2 = 0; s2 < 4; ++s2) {
        int c = ((2 * s2 + hb) ^ sl) * 8;
        bf16x8 av0 = *(const bf16x8*)(vbuf + l5 * 64 + c);
        bf16x8 av1 = *(const bf16x8*)(vbuf + (32 + l5) * 64 + c);
        u32 w0, w1, w2, w3;
        pl32swap(pA0[2 * s2], pA0[2 * s2 + 1], w0, w2);
        pl32swap(pB0[2 * s2], pB0[2 * s2 + 1], w1, w3);
        union { u32 u[4]; bf16x8 v; } bw0;
        bw0.u[0] = w0; bw0.u[1] = w1; bw0.u[2] = w2; bw0.u[3] = w3;
        oa00 = __builtin_amdgcn_mfma_f32_32x32x16_bf16(av0, bw0.v, oa00, 0, 0, 0);
        oa01 = __builtin_amdgcn_mfma_f32_32x32x16_bf16(av1, bw0.v, oa01, 0, 0, 0);
        pl32swap(pA1[2 * s2], pA1[2 * s2 + 1], w0, w2);
        pl32swap(pB1[2 * s2], pB1[2 * s2 + 1], w1, w3);
        union { u32 u[4]; bf16x8 v; } bw1;
        bw1.u[0] = w0; bw1.u[1] = w1; bw1.u[2] = w2; bw1.u[3] = w3;
        oa10 = __builtin_amdgcn_mfma_f32_32x32x16_bf16(av0, bw1.v, oa10, 0, 0, 0);
        oa11 = __builtin_amdgcn_mfma_f32_32x32x16_bf16(av1, bw1.v, oa11, 0, 0, 0);
      }
    }

    // ONE barrier per 128-key tile
    __builtin_amdgcn_sched_barrier(0);
    asm volatile("s_waitcnt vmcnt(0)" ::: "memory");
    __builtin_amdgcn_s_barrier();
    __builtin_amdgcn_sched_barrier(0);
    cur ^= 1;
  }

  // epilogue: combine hb halves of l; O^T lane layout: d = 32df+8r4+4hb+j, q=l5
  ls0 += __shfl_xor(ls0, 32);
  ls1 += __shfl_xor(ls1, 32);
  float inv0 = 1.0f / ls0;
  float inv1 = 1.0f / ls1;
  long row0 = (long)b * T_ + qs + l5;
  u16* ob0 = Aout + row0 * D_ + h * DH;
  u16* ob1 = ob0 + 32 * D_;            // row qs + 32 + l5
  #pragma unroll
  for (int r4 = 0; r4 < 4; ++r4) {
    u32 w0 = pack2(oa00[4 * r4 + 0] * inv0, oa00[4 * r4 + 1] * inv0);
    u32 w1 = pack2(oa00[4 * r4 + 2] * inv0, oa00[4 * r4 + 3] * inv0);
    *(uint2*)(ob0 + r4 * 8 + hb * 4) = make_uint2(w0, w1);
    u32 w2 = pack2(oa01[4 * r4 + 0] * inv0, oa01[4 * r4 + 1] * inv0);
    u32 w3 = pack2(oa01[4 * r4 + 2] * inv0, oa01[4 * r4 + 3] * inv0);
    *(uint2*)(ob0 + 32 + r4 * 8 + hb * 4) = make_uint2(w2, w3);
    u32 w4 = pack2(oa10[4 * r4 + 0] * inv1, oa10[4 * r4 + 1] * inv1);
    u32 w5 = pack2(oa10[4 * r4 + 2] * inv1, oa10[4 * r4 + 3] * inv1);
    *(uint2*)(ob1 + r4 * 8 + hb * 4) = make_uint2(w4, w5);
    u32 w6 = pack2(oa11[4 * r4 + 0] * inv1, oa11[4 * r4 + 1] * inv1);
    u32 w7 = pack2(oa11[4 * r4 + 2] * inv1, oa11[4 * r4 + 3] * inv1);
    *(uint2*)(ob1 + 32 + r4 * 8 + hb * 4) = make_uint2(w6, w7);
  }
}

// ---------------------------------------------------------------------------
extern "C" void kernel_launch(void* const* d_in, const int* in_sizes, int n_in,
                              void* d_out, int out_size, void* d_ws, size_t ws_size,
                              hipStream_t stream) {
  const float* x        = (const float*)d_in[0];
  const float* coords   = (const float*)d_in[1];
  const float* qkv_w    = (const float*)d_in[2];
  const float* qkv_b    = (const float*)d_in[3];
  const float* proj_w   = (const float*)d_in[4];
  const float* proj_b   = (const float*)d_in[5];
  const float* inv_freq = (const float*)d_in[6];
  const int*   axes     = (const int*)d_in[7];
  float* out = (float*)d_out;

  char* ws = (char*)d_ws;
  size_t off = 0;
  auto alloc = [&](size_t bytes) -> char* {
    char* p = ws + off;
    off += (bytes + 255) & ~(size_t)255;
    return p;
  };
  u16*   xb     = (u16*)  alloc((size_t)M_ROWS * D_ * 2);
  u16*   wqkv   = (u16*)  alloc((size_t)3 * D_ * D_ * 2);
  u16*   wproj  = (u16*)  alloc((size_t)D_ * D_ * 2);
  float* sc     = (float*)alloc((size_t)M_ROWS * 64 * 4);
  u16*   qr     = (u16*)  alloc((size_t)BH * T_ * DH * 2);
  u16*   kr     = (u16*)  alloc((size_t)BH * T_ * DH * 2);
  u16*   vt     = (u16*)  alloc((size_t)BH * T_ * DH * 2);
  u16*   aout   = (u16*)  alloc((size_t)BH * T_ * DH * 2);

  prep_kernel<<<7168, 256, 0, stream>>>(x, xb, qkv_w, wqkv, proj_w, wproj,
                                        coords, inv_freq, axes, sc);
  gemm_qkv<<<(M_ROWS / 128) * (3 * D_ / 128), 256, 0, stream>>>(xb, wqkv, qkv_b, sc,
                                                                qr, kr, vt);
  attn_kernel<<<512, 256, 0, stream>>>(qr, kr, vt, aout);
  gemm_bt<<<(M_ROWS / 128) * (D_ / 128), 256, 0, stream>>>(aout, wproj, proj_b, out,
                                                           M_ROWS, D_, D_);
}